// Round 10
// baseline (716.156 us; speedup 1.0000x reference)
//
#include <hip/hip_runtime.h>
#include <hip/hip_bf16.h>
#include <cstdint>
#include <cstddef>
#include <math.h>

typedef __bf16 bf16x8 __attribute__((ext_vector_type(8)));
typedef float  f32x4  __attribute__((ext_vector_type(4)));

#define DEVI __device__ __forceinline__

static constexpr int BB = 4096;   // batch
static constexpr int ZD = 256;    // Z_DIM

DEVI unsigned short f2bf(float f) {
  __bf16 h = (__bf16)f;
  return __builtin_bit_cast(unsigned short, h);
}
DEVI float bf2f(unsigned short u) {
  return (float)__builtin_bit_cast(__bf16, u);
}

DEVI void gload_lds16(const void* g, void* l) {
  __builtin_amdgcn_global_load_lds(
      (__attribute__((address_space(1))) void*)(g),
      (__attribute__((address_space(3))) void*)(l), 16, 0, 0);
}

// full bank-spread swizzle: XOR byte-bits 4-6 with row bits 0-2 (row = L>>7)
DEVI int swz(int L) { return L ^ (((L >> 7) & 7) << 4); }

// ---------------------------------------------------------------------------
// pack: x2 = [xh | xl] bf16 [4096][4096] from z_stack[m][b][z]
// ---------------------------------------------------------------------------
__global__ __launch_bounds__(256) void pack_x(
    const float* __restrict__ z, unsigned short* __restrict__ x2) {
  const int i = (blockIdx.x * 256 + threadIdx.x) * 4;   // linear idx in z
  const int m  = i >> 20;            // / (4096*256)
  const int r  = i & 1048575;
  const int b  = r >> 8;
  const int zd = r & 255;
  const float4 v = *(const float4*)(z + i);
  ushort4 h, l;
  h.x = f2bf(v.x); l.x = f2bf(v.x - bf2f(h.x));
  h.y = f2bf(v.y); l.y = f2bf(v.y - bf2f(h.y));
  h.z = f2bf(v.z); l.z = f2bf(v.z - bf2f(h.z));
  h.w = f2bf(v.w); l.w = f2bf(v.w - bf2f(h.w));
  const size_t o2 = (size_t)b * 4096 + m * ZD + zd;
  *(ushort4*)(x2 + o2) = h;
  *(ushort4*)(x2 + o2 + 2048) = l;
}

// ---------------------------------------------------------------------------
// one kernel for ALL weight transposes (f32 [R][C] -> bf16 [C][ldo], 32x32 tiles)
// ---------------------------------------------------------------------------
__global__ __launch_bounds__(256) void transpose_all(
    const float* __restrict__ Wq, const float* __restrict__ Wk,
    const float* __restrict__ Wv, const float* __restrict__ W1,
    const float* __restrict__ W2, const float* __restrict__ Wys,
    const float* __restrict__ Ws,
    unsigned short* __restrict__ Bqk, unsigned short* __restrict__ Wvt,
    unsigned short* __restrict__ W1t, unsigned short* __restrict__ W2t,
    unsigned short* __restrict__ Wyst, unsigned short* __restrict__ Wst) {
  __shared__ float tile[32][33];
  int b = blockIdx.x;
  const float* src;
  unsigned short* dh;
  int C, ldo, nbx, loff = 0;
  if (b < 8192) {                       // Wq, Wk -> Bqk (with lo at col+2048)
    const int which = b >> 12; b &= 4095;
    src = which ? Wk : Wq;
    dh = Bqk + (size_t)which * 2048 * 4096;
    C = 2048; ldo = 4096; nbx = 64; loff = 2048;
  } else if (b < 12288) { b -= 8192;  src = Wv;  dh = Wvt;  C = 2048; ldo = 2048; nbx = 64; }
  else if (b < 14336)   { b -= 12288; src = W1;  dh = W1t;  C = 1024; ldo = 2048; nbx = 32; }
  else if (b < 16384)   { b -= 14336; src = W2;  dh = W2t;  C = 2048; ldo = 1024; nbx = 64; }
  else if (b < 18432)   { b -= 16384; src = Wys; dh = Wyst; C = 1024; ldo = 2048; nbx = 32; }
  else {                                // Ws[m]: [1024][256] -> [256][1024]
    b -= 18432;
    const int m = b >> 8; b &= 255;
    src = Ws + (size_t)m * 262144;
    dh = Wst + (size_t)m * 262144;
    C = 256; ldo = 1024; nbx = 8;
  }
  const int c0 = (b % nbx) * 32, r0 = (b / nbx) * 32;
  const int tx = threadIdx.x, ty = threadIdx.y;   // (32,8)
#pragma unroll
  for (int k = 0; k < 4; ++k)
    tile[ty + 8 * k][tx] = src[(size_t)(r0 + ty + 8 * k) * C + (c0 + tx)];
  __syncthreads();
#pragma unroll
  for (int k = 0; k < 4; ++k) {
    const float f = tile[tx][ty + 8 * k];
    const size_t o = (size_t)(c0 + ty + 8 * k) * ldo + (r0 + tx);
    const unsigned short h = f2bf(f);
    dh[o] = h;
    if (loff) dh[o + loff] = f2bf(f - bf2f(h));
  }
}

// ---------------------------------------------------------------------------
// 256x256 8-phase GEMM, bf16 MFMA, f32 acc; compile-time geometry.
// SEG (KV=6144 virtual over 4096 storage):
//   A: [Xh | Xl | Xh]  (seg 2 -> k-4096) ; B: [Yh | Yh | Yl] (seg>=1 -> k-2048)
// SPLITK: 256 blocks = 128 tiles x 2 K-slices.
// EP 0: Cf[row*NN+col] = acc (f32)
// EP 1: split dual-output (q to Ob1, k to Ob2, hi/lo halves, +bias)
// Phase-ahead fragment prefetch: each phase issues the NEXT phase's ds_reads
// right after PH_SYNC so LDS service overlaps the MFMA burst (af/ag register
// double-buffer avoids WAR). Hazards: prefetched chunks always disjoint from
// concurrently-issued stage targets; every read completes (lgkmcnt(0) at its
// consuming phase) before the barrier preceding the stage that overwrites it.
// ---------------------------------------------------------------------------
#define DOMFMA(QI, QJ, AF, BF)                                            \
  {                                                                       \
    _Pragma("unroll") for (int ks = 0; ks < 2; ++ks) {                    \
      _Pragma("unroll") for (int f = 0; f < 4; ++f) {                     \
        _Pragma("unroll") for (int g = 0; g < 2; ++g) {                   \
          acc[(QI) * 4 + f][(QJ) * 2 + g] =                               \
              __builtin_amdgcn_mfma_f32_16x16x32_bf16(                    \
                  AF[f][ks], BF[g][ks], acc[(QI) * 4 + f][(QJ) * 2 + g],  \
                  0, 0, 0);                                               \
        }                                                                 \
      }                                                                   \
    }                                                                     \
  }

#define PH_SYNC()                                         \
  do {                                                    \
    __builtin_amdgcn_s_barrier();                         \
    asm volatile("s_waitcnt lgkmcnt(0)" ::: "memory");    \
    __builtin_amdgcn_sched_barrier(0);                    \
    __builtin_amdgcn_s_setprio(1);                        \
  } while (0)

#define PH_END()                                          \
  do {                                                    \
    __builtin_amdgcn_s_setprio(0);                        \
    __builtin_amdgcn_sched_barrier(0);                    \
    __builtin_amdgcn_s_barrier();                         \
  } while (0)

template<int EP, bool SEG, int SPLITK, int KV, int LDA, int LDB, int NN, int NBX>
__global__ __launch_bounds__(512, 2) void gemm256(
    const unsigned short* __restrict__ A,
    const unsigned short* __restrict__ Bt,
    const float* __restrict__ bias, const float* __restrict__ bias2,
    float* __restrict__ Cf,
    unsigned short* __restrict__ Ob1, unsigned short* __restrict__ Ob2) {
  extern __shared__ char lds[];            // 131072 B
  constexpr int NK = KV >> 6;
  const int t = threadIdx.x;               // 0..511
  const int lane = t & 63;
  const int w = t >> 6;
  const int wm = w >> 2, wn = w & 3;       // 2 x 4 waves
  const int lr = lane & 15, kg = lane >> 4;
  int bx, by;
  if constexpr (SPLITK) {
    // 256 blocks = 2 K-slices x (16 by x 8 bx); XCD gets contiguous bids
    const int bid = (blockIdx.x & 7) * 32 + (blockIdx.x >> 3);
    const int kslice = bid >> 7;
    const int tid2 = bid & 127;
    bx = tid2 & 7; by = tid2 >> 3;
    A  += kslice * (KV);                   // col offset within [*][LDA]
    Bt += kslice * (KV);
    Cf += (size_t)kslice * ((size_t)4096 * NN);
  } else if constexpr (NBX == 16) {
    // 2D XCD tiling: each XCD owns a 4x8 region of the 16x16 grid
    const int xcd = blockIdx.x & 7, i = blockIdx.x >> 3;
    by = (xcd >> 1) * 4 + (i >> 3);
    bx = (xcd & 1) * 8 + (i & 7);
  } else {
    const int q8 = gridDim.x >> 3;
    const int bid = (blockIdx.x & 7) * q8 + (blockIdx.x >> 3);
    bx = bid % NBX; by = bid / NBX;
  }
  const int Ar0 = by * 256, Br0 = bx * 256;

  // per-thread staging bases: linear LDS dest, inverse-swizzled global src
  const int Lb = t << 4;                   // byte offset 0..8176
  const int rowL = Lb >> 7;                // source row within 64-chunk
  const int colb = swz(Lb) & 127;          // swizzled byte col within row
  const char* Abase = (const char*)A + (size_t)(Ar0 + rowL) * LDA * 2 + colb;
  const char* Bbase = (const char*)Bt + (size_t)(Br0 + rowL) * LDB * 2 + colb;
  constexpr size_t ldaB = (size_t)LDA * 128;   // bytes per 64 rows
  constexpr size_t ldbB = (size_t)LDB * 128;
  char* const ldw = lds + ((t >> 6) << 10);

  // hoisted LDS read bases (identity: swz(row*128+k) = row*128 + (k ^ Cx))
  const int Cx = (lane & 7) << 4;
  const int baseA0 = wm * 16384 + lr * 128 + ((kg * 16) ^ Cx);
  const int baseA1 = wm * 16384 + lr * 128 + ((64 + kg * 16) ^ Cx);
  const int baseB0 = 32768 + wn * 8192 + lr * 128 + ((kg * 16) ^ Cx);
  const int baseB1 = 32768 + wn * 8192 + lr * 128 + ((64 + kg * 16) ^ Cx);

  auto stageA = [&](int c, int kk, int dst_off) {
    gload_lds16(Abase + (size_t)c * ldaB + ((unsigned)kk << 1), ldw + dst_off);
  };
  auto stageB = [&](int c, int kk, int dst_off) {
    gload_lds16(Bbase + (size_t)c * ldbB + ((unsigned)kk << 1), ldw + dst_off);
  };
  auto rdA = [&](const char* buf, int qi, int f, int ks) {
    return *(const bf16x8*)(buf + (ks ? baseA1 : baseA0) + qi * 8192 + f * 2048);
  };
  auto rdB = [&](const char* buf, int qj, int g, int ks) {
    return *(const bf16x8*)(buf + (ks ? baseB1 : baseB0) + qj * 4096 + g * 2048);
  };
  // segment remap: virtual k0 -> storage k for A and B
  auto kA = [](int k0) { return SEG ? (k0 - ((k0 >> 11) == 2 ? 4096 : 0)) : k0; };
  auto kB = [](int k0) { return SEG ? (k0 - ((k0 >> 11) >= 1 ? 2048 : 0)) : k0; };

  f32x4 acc[8][4] = {};
  bf16x8 af[4][2], ag[4][2], b0[2][2], b1[2][2];

  // ---- prologue: tile0 (8 chunks) + tile1 first 6 chunks; prefetch ph0 ----
  {
    stageA(0, kA(0), 0);
    stageA(1, kA(0), 8192);
    stageA(2, kA(0), 16384);
    stageA(3, kA(0), 24576);
    stageB(0, kB(0), 32768);
    stageB(1, kB(0), 40960);
    stageB(2, kB(0), 49152);
    stageB(3, kB(0), 57344);
    stageA(0, kA(64), 65536 + 0);
    stageA(2, kA(64), 65536 + 16384);
    stageB(0, kB(64), 65536 + 32768);
    stageB(1, kB(64), 65536 + 40960);
    stageB(2, kB(64), 65536 + 49152);
    stageB(3, kB(64), 65536 + 57344);
    asm volatile("s_waitcnt vmcnt(6)" ::: "memory");
    __builtin_amdgcn_sched_barrier(0);
    __builtin_amdgcn_s_barrier();
    // prefetch tile0 phase-0 fragments (A qi=0, B qj=0) from buffer 0
#pragma unroll
    for (int f = 0; f < 4; ++f)
#pragma unroll
      for (int ks = 0; ks < 2; ++ks) af[f][ks] = rdA(lds, 0, f, ks);
#pragma unroll
    for (int g = 0; g < 2; ++g)
#pragma unroll
      for (int ks = 0; ks < 2; ++ks) b0[g][ks] = rdB(lds, 0, g, ks);
    __builtin_amdgcn_sched_barrier(0);
  }

  for (int tt = 0; tt < NK; ++tt) {
    const int cur = tt & 1;
    const char* buf  = lds + cur * 65536;
    const char* nbuf = lds + (cur ^ 1) * 65536;
    const int curo = cur * 65536, nxto = (cur ^ 1) * 65536;
    const int k1 = (tt + 1) * 64, k2 = (tt + 2) * 64;

    // ---- phase 0: stage tile+1 A1,A3; MFMA(0,0) af*b0; prefetch b1 ----
    if (tt + 1 < NK) {
      stageA(1, kA(k1), nxto + 8192);
      stageA(3, kA(k1), nxto + 24576);
    }
    PH_SYNC();
#pragma unroll
    for (int g = 0; g < 2; ++g)
#pragma unroll
      for (int ks = 0; ks < 2; ++ks) b1[g][ks] = rdB(buf, 1, g, ks);
    __builtin_amdgcn_sched_barrier(0);
    DOMFMA(0, 0, af, b0);
    PH_END();

    // ---- phase 1: stage tile+2 A0,A2; MFMA(0,1) af*b1; prefetch ag ----
    if (tt + 2 < NK) {
      stageA(0, kA(k2), curo + 0);
      stageA(2, kA(k2), curo + 16384);
    }
    PH_SYNC();
#pragma unroll
    for (int f = 0; f < 4; ++f)
#pragma unroll
      for (int ks = 0; ks < 2; ++ks) ag[f][ks] = rdA(buf, 1, f, ks);
    __builtin_amdgcn_sched_barrier(0);
    DOMFMA(0, 1, af, b1);
    PH_END();

    // ---- phase 2: stage tile+2 B0,B1; MFMA(1,0) ag*b0 ----
    if (tt + 2 < NK) {
      stageB(0, kB(k2), curo + 32768);
      stageB(1, kB(k2), curo + 40960);
    }
    PH_SYNC();
    DOMFMA(1, 0, ag, b0);
    PH_END();

    // ---- phase 3: stage tile+2 B2,B3; vmcnt(6); MFMA(1,1); prefetch next ----
    if (tt + 2 < NK) {
      stageB(2, kB(k2), curo + 49152);
      stageB(3, kB(k2), curo + 57344);
      asm volatile("s_waitcnt vmcnt(6)" ::: "memory");
    } else {
      asm volatile("s_waitcnt vmcnt(0)" ::: "memory");
    }
    __builtin_amdgcn_sched_barrier(0);
    PH_SYNC();
    if (tt + 1 < NK) {
      // next tile's phase-0 fragments from nbuf (all landed per vmcnt chain)
#pragma unroll
      for (int f = 0; f < 4; ++f)
#pragma unroll
        for (int ks = 0; ks < 2; ++ks) af[f][ks] = rdA(nbuf, 0, f, ks);
#pragma unroll
      for (int g = 0; g < 2; ++g)
#pragma unroll
        for (int ks = 0; ks < 2; ++ks) b0[g][ks] = rdB(nbuf, 0, g, ks);
    }
    __builtin_amdgcn_sched_barrier(0);
    DOMFMA(1, 1, ag, b1);
    PH_END();
  }

  // ---- epilogue ----
  const int rbase = Ar0 + wm * 128 + kg * 4;
  const int cbase = Br0 + wn * 64 + lr;
#pragma unroll
  for (int rf = 0; rf < 8; ++rf) {
#pragma unroll
    for (int cf = 0; cf < 4; ++cf) {
      const int col = cbase + cf * 16;
#pragma unroll
      for (int q = 0; q < 4; ++q) {
        const int row = rbase + rf * 16 + q;
        float val = acc[rf][cf][q];
        if constexpr (EP == 0) {
          Cf[(size_t)row * NN + col] = val;
        } else {
          if (col < 2048) {
            val += bias[col];
            const unsigned short h = f2bf(val);
            Ob1[(size_t)row * 4096 + col] = h;
            Ob1[(size_t)row * 4096 + 2048 + col] = f2bf(val - bf2f(h));
          } else {
            const int c2 = col - 2048;
            val += bias2[c2];
            const unsigned short h = f2bf(val);
            Ob2[(size_t)row * 4096 + c2] = h;
            Ob2[(size_t)row * 4096 + 2048 + c2] = f2bf(val - bf2f(h));
          }
        }
      }
    }
  }
}

// ---------------------------------------------------------------------------
// GEMM: C[M][N] = A[M][K] @ Bt[N][K]^T  (bf16 MFMA, f32 acc), m97 structure.
// EP: 0=f32(+bias) 1=bf16(+bias) 2=gelu->bf16 4=perm [m][b][z] 5=bf16(+row bias)
// ---------------------------------------------------------------------------
template<int EP>
__global__ __launch_bounds__(256) void gemm_bt(
    const unsigned short* __restrict__ Ah,
    const unsigned short* __restrict__ Bh,
    const float* __restrict__ bias,
    float* __restrict__ Cf, unsigned short* __restrict__ Cb,
    int M, int N, int K, int lda, int ldb) {
  __shared__ unsigned short lds[2][128 * 32];
  const int t = threadIdx.x;
  const int lane = t & 63;
  const int w = t >> 6;
  const int wr = (w >> 1) * 64, wc = (w & 1) * 64;
  const int lr = lane & 15, kg = lane >> 4;
  const size_t Ar0 = (size_t)blockIdx.y * 128;
  const size_t Br0 = (size_t)blockIdx.x * 128;

  f32x4 acc[4][4] = {};

  for (int k0 = 0; k0 < K; k0 += 32) {
#pragma unroll
    for (int rnd = 0; rnd < 2; ++rnd) {
      const int e = t * 8 + rnd * 2048;
      const int row = e >> 5, col = e & 31;
      const size_t ga = (Ar0 + row) * (size_t)lda + (k0 + col);
      const size_t gb = (Br0 + row) * (size_t)ldb + (k0 + col);
      const int lo = (w << 9) + rnd * 2048;   // wave-uniform LDS elem offset
      gload_lds16(Ah + ga, &lds[0][lo]);
      gload_lds16(Bh + gb, &lds[1][lo]);
    }
    __syncthreads();
    bf16x8 ah[4], bh[4];
#pragma unroll
    for (int i = 0; i < 4; ++i) {
      ah[i] = *(const bf16x8*)&lds[0][((wr + i * 16 + lr) << 5) + (kg << 3)];
      bh[i] = *(const bf16x8*)&lds[1][((wc + i * 16 + lr) << 5) + (kg << 3)];
    }
#pragma unroll
    for (int i = 0; i < 4; ++i)
#pragma unroll
      for (int j = 0; j < 4; ++j)
        acc[i][j] = __builtin_amdgcn_mfma_f32_16x16x32_bf16(ah[i], bh[j], acc[i][j], 0, 0, 0);
    __syncthreads();
  }

  const int rb = (int)Ar0 + wr + (lane >> 4) * 4;
  const int cb = (int)Br0 + wc + lr;
#pragma unroll
  for (int i = 0; i < 4; ++i) {
#pragma unroll
    for (int j = 0; j < 4; ++j) {
      const int col = cb + j * 16;
      const float bsv = (EP == 5) ? 0.0f : (bias ? bias[col] : 0.0f);
#pragma unroll
      for (int q = 0; q < 4; ++q) {
        const int row = rb + i * 16 + q;
        const float val = acc[i][j][q] + bsv;
        const size_t o = (size_t)row * N + col;
        if constexpr (EP == 0) {
          Cf[o] = val;
        } else if constexpr (EP == 1) {
          Cb[o] = f2bf(val);
        } else if constexpr (EP == 2) {
          const float ge = 0.5f * val * (1.0f + erff(val * 0.70710678118654752f));
          Cb[o] = f2bf(ge);
        } else if constexpr (EP == 4) {
          const size_t oo = (size_t)(col >> 8) * ((size_t)BB * ZD)
                          + (size_t)row * ZD + (col & 255);
          Cf[oo] = val;
        } else {  // EP == 5: bf16 with ROW bias
          Cb[o] = f2bf(val + bias[row]);
        }
      }
    }
  }
}

// ---------------------------------------------------------------------------
// row softmax over 4096 cols, f32 in -> bf16 out
// ---------------------------------------------------------------------------
__global__ __launch_bounds__(256) void softmax_rows(const float* __restrict__ S,
                                                    unsigned short* __restrict__ P) {
  const int row = blockIdx.x;
  const int t = threadIdx.x;
  const int lane = t & 63, w = t >> 6;
  const float* s = S + (size_t)row * 4096;
  float4 v[4];
  float mx = -3.4e38f;
#pragma unroll
  for (int i = 0; i < 4; ++i) {
    v[i] = *(const float4*)(s + (size_t)(t + 256 * i) * 4);
    mx = fmaxf(mx, fmaxf(fmaxf(v[i].x, v[i].y), fmaxf(v[i].z, v[i].w)));
  }
#pragma unroll
  for (int off = 32; off >= 1; off >>= 1) mx = fmaxf(mx, __shfl_xor(mx, off));
  __shared__ float redm[4], redsum[4];
  if (lane == 0) redm[w] = mx;
  __syncthreads();
  mx = fmaxf(fmaxf(redm[0], redm[1]), fmaxf(redm[2], redm[3]));
  float sum = 0.f;
#pragma unroll
  for (int i = 0; i < 4; ++i) {
    v[i].x = expf(v[i].x - mx);
    v[i].y = expf(v[i].y - mx);
    v[i].z = expf(v[i].z - mx);
    v[i].w = expf(v[i].w - mx);
    sum += v[i].x + v[i].y + v[i].z + v[i].w;
  }
#pragma unroll
  for (int off = 32; off >= 1; off >>= 1) sum += __shfl_xor(sum, off);
  if (lane == 0) redsum[w] = sum;
  __syncthreads();
  sum = redsum[0] + redsum[1] + redsum[2] + redsum[3];
  const float inv = 1.0f / sum;
  unsigned short* p = P + (size_t)row * 4096;
#pragma unroll
  for (int i = 0; i < 4; ++i) {
    ushort4 u;
    u.x = f2bf(v[i].x * inv);
    u.y = f2bf(v[i].y * inv);
    u.z = f2bf(v[i].z * inv);
    u.w = f2bf(v[i].w * inv);
    *(ushort4*)(p + (size_t)(t + 256 * i) * 4) = u;
  }
}

// ---------------------------------------------------------------------------
// layernorm(a + b [+ c]) over 2048 cols; writes bf16 (and optionally f32)
// ZG: 'a' is z_stack [8][4096][256] gathered as x[row][m*256+zd]
// ---------------------------------------------------------------------------
template<bool ZG, bool WF32>
__global__ __launch_bounds__(256) void ln_fused(
    const float* __restrict__ a, const float* __restrict__ b,
    const float* __restrict__ c,
    const float* __restrict__ g, const float* __restrict__ be,
    float* __restrict__ of, unsigned short* __restrict__ ob) {
  const int row = blockIdx.x;
  const int t = threadIdx.x;
  const int lane = t & 63, w = t >> 6;
  const float* br = b + (size_t)row * 2048;
  float4 x[2];
  float s = 0.f, ss = 0.f;
#pragma unroll
  for (int i = 0; i < 2; ++i) {
    const int o = (t + 256 * i) * 4;
    float4 av;
    if constexpr (ZG) {
      av = *(const float4*)(a + ((size_t)(o >> 8) * 4096 + row) * 256 + (o & 255));
    } else {
      av = *(const float4*)(a + (size_t)row * 2048 + o);
    }
    const float4 bv = *(const float4*)(br + o);
    x[i].x = av.x + bv.x; x[i].y = av.y + bv.y;
    x[i].z = av.z + bv.z; x[i].w = av.w + bv.w;
    if (c) {
      const float4 cv = *(const float4*)(c + (size_t)row * 2048 + o);
      x[i].x += cv.x; x[i].y += cv.y; x[i].z += cv.z; x[i].w += cv.w;
    }
    s  += x[i].x + x[i].y + x[i].z + x[i].w;
    ss += x[i].x * x[i].x + x[i].y * x[i].y + x[i].z * x[i].z + x[i].w * x[i].w;
  }
#pragma unroll
  for (int off = 32; off >= 1; off >>= 1) {
    s  += __shfl_xor(s, off);
    ss += __shfl_xor(ss, off);
  }
  __shared__ float rs[4], rss[4];
  if (lane == 0) { rs[w] = s; rss[w] = ss; }
  __syncthreads();
  s  = rs[0] + rs[1] + rs[2] + rs[3];
  ss = rss[0] + rss[1] + rss[2] + rss[3];
  const float mu  = s * (1.0f / 2048.0f);
  const float var = ss * (1.0f / 2048.0f) - mu * mu;
  const float inv = rsqrtf(var + 1e-5f);
#pragma unroll
  for (int i = 0; i < 2; ++i) {
    const int o = (t + 256 * i) * 4;
    const float4 gv  = *(const float4*)(g + o);
    const float4 bev = *(const float4*)(be + o);
    float4 y;
    y.x = (x[i].x - mu) * inv * gv.x + bev.x;
    y.y = (x[i].y - mu) * inv * gv.y + bev.y;
    y.z = (x[i].z - mu) * inv * gv.z + bev.z;
    y.w = (x[i].w - mu) * inv * gv.w + bev.w;
    if constexpr (WF32) *(float4*)(of + (size_t)row * 2048 + o) = y;
    ushort4 u;
    u.x = f2bf(y.x); u.y = f2bf(y.y); u.z = f2bf(y.z); u.w = f2bf(y.w);
    *(ushort4*)(ob + (size_t)row * 2048 + o) = u;
  }
}

// ---------------------------------------------------------------------------
extern "C" void kernel_launch(void* const* d_in, const int* in_sizes, int n_in,
                              void* d_out, int out_size, void* d_ws, size_t ws_size,
                              hipStream_t stream) {
  (void)in_sizes; (void)n_in; (void)out_size;
  const float* z    = (const float*)d_in[0];
  const float* Wq   = (const float*)d_in[1];
  const float* bq   = (const float*)d_in[2];
  const float* Wk   = (const float*)d_in[3];
  const float* bk   = (const float*)d_in[4];
  const float* Wv   = (const float*)d_in[5];
  const float* bv   = (const float*)d_in[6];
  const float* W1   = (const float*)d_in[7];
  const float* b1   = (const float*)d_in[8];
  const float* W2   = (const float*)d_in[9];
  const float* b2   = (const float*)d_in[10];
  const float* ln1g = (const float*)d_in[11];
  const float* ln1b = (const float*)d_in[12];
  const float* ln2g = (const float*)d_in[13];
  const float* ln2b = (const float*)d_in[14];
  const float* Wys  = (const float*)d_in[15];
  const float* bys  = (const float*)d_in[16];
  const float* Ws   = (const float*)d_in[17];
  const float* bs   = (const float*)d_in[18];
  float* out = (float*)d_out;
  char* ws = (char*)d_ws;

  // ---- workspace arena (lifetime-aliased), 216 MB total ----
  const size_t MB = 1048576;
  const size_t off_h2   = 0;          // f32 [4096][2048], MLP2 out
  const size_t off_x2   = 32 * MB;    // bf16 [4096][4096] [xh|xl], until QKproj
  const size_t off_S    = 32 * MB;    // f32 [4096][4096], after QKproj, until softmax
  const size_t off_att  = 32 * MB;    // f32 2x[4096][2048] split-K partials, after softmax
  const size_t off_Bqk  = 64 * MB;    // bf16 [4096][4096], until QKproj
  const size_t off_Aq   = 96 * MB;    // bf16 [4096][4096] [qh|ql], until S
  const size_t off_P    = 96 * MB;    // bf16 [4096][4096], after S, until PV
  const size_t off_x1f  = 96 * MB;    // f32 [4096][2048], after PV
  const size_t off_Btk  = 128 * MB;   // bf16 [4096][4096] [kh|kl], until S
  const size_t off_hmid = 128 * MB;   // bf16 [4096][1024], after S
  const size_t off_ybbf = 136 * MB;   // bf16 [4096][1024]
  const size_t off_x1bf = 160 * MB;   // bf16 [4096][2048], LN1 out
  const size_t off_Vt   = 176 * MB;   // bf16 [2048][4096], until PV
  const size_t off_x2bf = 176 * MB;   // bf16 [4096][2048], after PV
  const size_t off_Wvt  = 192 * MB;   // bf16 [2048][2048]
  const size_t off_W1t  = 200 * MB;   // bf16 [1024][2048]
  const size_t off_W2t  = 204 * MB;   // bf16 [2048][1024]
  const size_t off_Wyst = 208 * MB;   // bf16 [1024][2048]
  const size_t off_Wst  = 212 * MB;   // bf16 8x[256][1024]
  if (ws_size < 216 * MB) return;

#define F32P(o) ((float*)(ws + (o)))
#define BFP(o)  ((unsigned short*)(ws + (o)))

  const int LDSB = 131072;

  // prep (2 launches)
  pack_x<<<8192, 256, 0, stream>>>(z, BFP(off_x2));
  transpose_all<<<20480, dim3(32, 8), 0, stream>>>(Wq, Wk, Wv, W1, W2, Wys, Ws,
      BFP(off_Bqk), BFP(off_Wvt), BFP(off_W1t), BFP(off_W2t), BFP(off_Wyst), BFP(off_Wst));

  // Vt = Wv^T @ x^T directly (M=2048 n-rows, N=4096 batch, row bias bv)
  gemm_bt<5><<<dim3(32, 16), 256, 0, stream>>>(BFP(off_Wvt), BFP(off_x2), bv,
      nullptr, BFP(off_Vt), 2048, 4096, 2048, 2048, 4096);

  // fused Q+K projection with hi/lo split epilogue (K=6144 virtual)  [8-phase]
  gemm256<1, true, 0, 6144, 4096, 4096, 4096, 16><<<256, 512, LDSB, stream>>>(
      BFP(off_x2), BFP(off_Bqk), bq, bk, nullptr, BFP(off_Aq), BFP(off_Btk));

  // S = q @ k^T with split (K=6144 virtual), f32 out  [8-phase]
  gemm256<0, true, 0, 6144, 4096, 4096, 4096, 16><<<256, 512, LDSB, stream>>>(
      BFP(off_Aq), BFP(off_Btk), nullptr, nullptr, F32P(off_S), nullptr, nullptr);

  // softmax -> P (bf16); att = P @ V via split-K=2 gemm256 (partials att0,att1)
  softmax_rows<<<4096, 256, 0, stream>>>(F32P(off_S), BFP(off_P));
  gemm256<0, false, 1, 2048, 4096, 4096, 2048, 8><<<256, 512, LDSB, stream>>>(
      BFP(off_P), BFP(off_Vt), nullptr, nullptr, F32P(off_att), nullptr, nullptr);
  ln_fused<true, true ><<<4096, 256, 0, stream>>>(z, F32P(off_att),
      F32P(off_att + 32 * MB), ln1g, ln1b, F32P(off_x1f), BFP(off_x1bf));

  // MLP  [m97 structure]
  gemm_bt<2><<<dim3(8, 32), 256, 0, stream>>>(BFP(off_x1bf), BFP(off_W1t), b1,
      nullptr, BFP(off_hmid), 4096, 1024, 2048, 2048, 2048);
  gemm_bt<0><<<dim3(16, 32), 256, 0, stream>>>(BFP(off_hmid), BFP(off_W2t), b2,
      F32P(off_h2), nullptr, 4096, 2048, 1024, 1024, 1024);
  ln_fused<false, false><<<4096, 256, 0, stream>>>(F32P(off_x1f), F32P(off_h2),
      nullptr, ln2g, ln2b, nullptr, BFP(off_x2bf));

  // output head  [m97 structure]
  gemm_bt<1><<<dim3(8, 32), 256, 0, stream>>>(BFP(off_x2bf), BFP(off_Wyst), bys,
      nullptr, BFP(off_ybbf), 4096, 1024, 2048, 2048, 2048);
  gemm_bt<4><<<dim3(16, 32), 256, 0, stream>>>(BFP(off_ybbf), BFP(off_Wst), bs,
      out, nullptr, 4096, 2048, 1024, 1024, 1024);
}

// Round 11
// 706.777 us; speedup vs baseline: 1.0133x; 1.0133x over previous
//
#include <hip/hip_runtime.h>
#include <hip/hip_bf16.h>
#include <cstdint>
#include <cstddef>
#include <math.h>

typedef __bf16 bf16x8 __attribute__((ext_vector_type(8)));
typedef float  f32x4  __attribute__((ext_vector_type(4)));

#define DEVI __device__ __forceinline__

static constexpr int BB = 4096;   // batch
static constexpr int ZD = 256;    // Z_DIM

DEVI unsigned short f2bf(float f) {
  __bf16 h = (__bf16)f;
  return __builtin_bit_cast(unsigned short, h);
}
DEVI float bf2f(unsigned short u) {
  return (float)__builtin_bit_cast(__bf16, u);
}

DEVI void gload_lds16(const void* g, void* l) {
  __builtin_amdgcn_global_load_lds(
      (__attribute__((address_space(1))) void*)(g),
      (__attribute__((address_space(3))) void*)(l), 16, 0, 0);
}

// full bank-spread swizzle: XOR byte-bits 4-6 with row bits 0-2 (row = L>>7)
DEVI int swz(int L) { return L ^ (((L >> 7) & 7) << 4); }

// ---------------------------------------------------------------------------
// pack: x2 = [xh | xl] bf16 [4096][4096] from z_stack[m][b][z]
// ---------------------------------------------------------------------------
__global__ __launch_bounds__(256) void pack_x(
    const float* __restrict__ z, unsigned short* __restrict__ x2) {
  const int i = (blockIdx.x * 256 + threadIdx.x) * 4;   // linear idx in z
  const int m  = i >> 20;            // / (4096*256)
  const int r  = i & 1048575;
  const int b  = r >> 8;
  const int zd = r & 255;
  const float4 v = *(const float4*)(z + i);
  ushort4 h, l;
  h.x = f2bf(v.x); l.x = f2bf(v.x - bf2f(h.x));
  h.y = f2bf(v.y); l.y = f2bf(v.y - bf2f(h.y));
  h.z = f2bf(v.z); l.z = f2bf(v.z - bf2f(h.z));
  h.w = f2bf(v.w); l.w = f2bf(v.w - bf2f(h.w));
  const size_t o2 = (size_t)b * 4096 + m * ZD + zd;
  *(ushort4*)(x2 + o2) = h;
  *(ushort4*)(x2 + o2 + 2048) = l;
}

// ---------------------------------------------------------------------------
// one kernel for ALL weight transposes (f32 [R][C] -> bf16 [C][ldo], 32x32 tiles)
// ---------------------------------------------------------------------------
__global__ __launch_bounds__(256) void transpose_all(
    const float* __restrict__ Wq, const float* __restrict__ Wk,
    const float* __restrict__ Wv, const float* __restrict__ W1,
    const float* __restrict__ W2, const float* __restrict__ Wys,
    const float* __restrict__ Ws,
    unsigned short* __restrict__ Bqk, unsigned short* __restrict__ Wvt,
    unsigned short* __restrict__ W1t, unsigned short* __restrict__ W2t,
    unsigned short* __restrict__ Wyst, unsigned short* __restrict__ Wst) {
  __shared__ float tile[32][33];
  int b = blockIdx.x;
  const float* src;
  unsigned short* dh;
  int C, ldo, nbx, loff = 0;
  if (b < 8192) {                       // Wq, Wk -> Bqk (with lo at col+2048)
    const int which = b >> 12; b &= 4095;
    src = which ? Wk : Wq;
    dh = Bqk + (size_t)which * 2048 * 4096;
    C = 2048; ldo = 4096; nbx = 64; loff = 2048;
  } else if (b < 12288) { b -= 8192;  src = Wv;  dh = Wvt;  C = 2048; ldo = 2048; nbx = 64; }
  else if (b < 14336)   { b -= 12288; src = W1;  dh = W1t;  C = 1024; ldo = 2048; nbx = 32; }
  else if (b < 16384)   { b -= 14336; src = W2;  dh = W2t;  C = 2048; ldo = 1024; nbx = 64; }
  else if (b < 18432)   { b -= 16384; src = Wys; dh = Wyst; C = 1024; ldo = 2048; nbx = 32; }
  else {                                // Ws[m]: [1024][256] -> [256][1024]
    b -= 18432;
    const int m = b >> 8; b &= 255;
    src = Ws + (size_t)m * 262144;
    dh = Wst + (size_t)m * 262144;
    C = 256; ldo = 1024; nbx = 8;
  }
  const int c0 = (b % nbx) * 32, r0 = (b / nbx) * 32;
  const int tx = threadIdx.x, ty = threadIdx.y;   // (32,8)
#pragma unroll
  for (int k = 0; k < 4; ++k)
    tile[ty + 8 * k][tx] = src[(size_t)(r0 + ty + 8 * k) * C + (c0 + tx)];
  __syncthreads();
#pragma unroll
  for (int k = 0; k < 4; ++k) {
    const float f = tile[tx][ty + 8 * k];
    const size_t o = (size_t)(c0 + ty + 8 * k) * ldo + (r0 + tx);
    const unsigned short h = f2bf(f);
    dh[o] = h;
    if (loff) dh[o + loff] = f2bf(f - bf2f(h));
  }
}

// ---------------------------------------------------------------------------
// 256x256 8-phase GEMM, bf16 MFMA, f32 acc; compile-time geometry.
// SEG (KV=6144 virtual over 4096 storage):
//   A: [Xh | Xl | Xh]  (seg 2 -> k-4096) ; B: [Yh | Yh | Yl] (seg>=1 -> k-2048)
// SPLITK: 256 blocks = 128 tiles x 2 K-slices.
// EP 0: Cf[row*NN+col] = acc (f32)
// EP 1: split dual-output (q to Ob1, k to Ob2, hi/lo halves, +bias)
// ---------------------------------------------------------------------------
#define DOMFMA(QI, QJ, AF, BF)                                            \
  {                                                                       \
    _Pragma("unroll") for (int ks = 0; ks < 2; ++ks) {                    \
      _Pragma("unroll") for (int f = 0; f < 4; ++f) {                     \
        _Pragma("unroll") for (int g = 0; g < 2; ++g) {                   \
          acc[(QI) * 4 + f][(QJ) * 2 + g] =                               \
              __builtin_amdgcn_mfma_f32_16x16x32_bf16(                    \
                  AF[f][ks], BF[g][ks], acc[(QI) * 4 + f][(QJ) * 2 + g],  \
                  0, 0, 0);                                               \
        }                                                                 \
      }                                                                   \
    }                                                                     \
  }

#define PH_SYNC()                                         \
  do {                                                    \
    __builtin_amdgcn_s_barrier();                         \
    asm volatile("s_waitcnt lgkmcnt(0)" ::: "memory");    \
    __builtin_amdgcn_sched_barrier(0);                    \
    __builtin_amdgcn_s_setprio(1);                        \
  } while (0)

#define PH_END()                                          \
  do {                                                    \
    __builtin_amdgcn_s_setprio(0);                        \
    __builtin_amdgcn_sched_barrier(0);                    \
    __builtin_amdgcn_s_barrier();                         \
  } while (0)

template<int EP, bool SEG, int SPLITK, int KV, int LDA, int LDB, int NN, int NBX>
__global__ __launch_bounds__(512, 2) void gemm256(
    const unsigned short* __restrict__ A,
    const unsigned short* __restrict__ Bt,
    const float* __restrict__ bias, const float* __restrict__ bias2,
    float* __restrict__ Cf,
    unsigned short* __restrict__ Ob1, unsigned short* __restrict__ Ob2) {
  extern __shared__ char lds[];            // 131072 B
  constexpr int NK = KV >> 6;
  const int t = threadIdx.x;               // 0..511
  const int lane = t & 63;
  const int w = t >> 6;
  const int wm = w >> 2, wn = w & 3;       // 2 x 4 waves
  const int lr = lane & 15, kg = lane >> 4;
  int bx, by;
  if constexpr (SPLITK) {
    // 256 blocks = 2 K-slices x (16 by x 8 bx); XCD gets contiguous bids
    const int bid = (blockIdx.x & 7) * 32 + (blockIdx.x >> 3);
    const int kslice = bid >> 7;
    const int tid2 = bid & 127;
    bx = tid2 & 7; by = tid2 >> 3;
    A  += kslice * (KV);                   // col offset within [*][LDA]
    Bt += kslice * (KV);
    Cf += (size_t)kslice * ((size_t)4096 * NN);
  } else if constexpr (NBX == 16) {
    // 2D XCD tiling: each XCD owns a 4x8 region of the 16x16 grid
    const int xcd = blockIdx.x & 7, i = blockIdx.x >> 3;
    by = (xcd >> 1) * 4 + (i >> 3);
    bx = (xcd & 1) * 8 + (i & 7);
  } else {
    const int q8 = gridDim.x >> 3;
    const int bid = (blockIdx.x & 7) * q8 + (blockIdx.x >> 3);
    bx = bid % NBX; by = bid / NBX;
  }
  const int Ar0 = by * 256, Br0 = bx * 256;

  // per-thread staging bases: linear LDS dest, inverse-swizzled global src
  const int Lb = t << 4;                   // byte offset 0..8176
  const int rowL = Lb >> 7;                // source row within 64-chunk
  const int colb = swz(Lb) & 127;          // swizzled byte col within row
  const char* Abase = (const char*)A + (size_t)(Ar0 + rowL) * LDA * 2 + colb;
  const char* Bbase = (const char*)Bt + (size_t)(Br0 + rowL) * LDB * 2 + colb;
  constexpr size_t ldaB = (size_t)LDA * 128;   // bytes per 64 rows
  constexpr size_t ldbB = (size_t)LDB * 128;
  char* const ldw = lds + ((t >> 6) << 10);

  auto stageA = [&](int c, int kk, int dst_off) {
    gload_lds16(Abase + (size_t)c * ldaB + ((unsigned)kk << 1), ldw + dst_off);
  };
  auto stageB = [&](int c, int kk, int dst_off) {
    gload_lds16(Bbase + (size_t)c * ldbB + ((unsigned)kk << 1), ldw + dst_off);
  };
  auto rdA = [&](const char* buf, int qi, int f, int ks) {
    const int L = swz(((qi * 64 + f * 16 + lr) << 7) + ks * 64 + kg * 16);
    return *(const bf16x8*)(buf + wm * 16384 + L);
  };
  auto rdB = [&](const char* buf, int qj, int g, int ks) {
    const int L = swz(((wn * 64 + qj * 32 + g * 16 + lr) << 7) + ks * 64 + kg * 16);
    return *(const bf16x8*)(buf + 32768 + L);
  };
  // segment remap: virtual k0 -> storage k for A and B
  auto kA = [](int k0) { return SEG ? (k0 - ((k0 >> 11) == 2 ? 4096 : 0)) : k0; };
  auto kB = [](int k0) { return SEG ? (k0 - ((k0 >> 11) >= 1 ? 2048 : 0)) : k0; };

  f32x4 acc[8][4] = {};
  bf16x8 af[4][2], b0[2][2], b1[2][2];

  // ---- prologue: tile0 (8 chunks) + tile1 first 6 chunks ----
  {
    stageA(0, kA(0), 0);
    stageA(1, kA(0), 8192);
    stageA(2, kA(0), 16384);
    stageA(3, kA(0), 24576);
    stageB(0, kB(0), 32768);
    stageB(1, kB(0), 40960);
    stageB(2, kB(0), 49152);
    stageB(3, kB(0), 57344);
    stageA(0, kA(64), 65536 + 0);
    stageA(2, kA(64), 65536 + 16384);
    stageB(0, kB(64), 65536 + 32768);
    stageB(1, kB(64), 65536 + 40960);
    stageB(2, kB(64), 65536 + 49152);
    stageB(3, kB(64), 65536 + 57344);
    asm volatile("s_waitcnt vmcnt(6)" ::: "memory");
    __builtin_amdgcn_sched_barrier(0);
    __builtin_amdgcn_s_barrier();
  }

  for (int tt = 0; tt < NK; ++tt) {
    const int cur = tt & 1;
    const char* buf = lds + cur * 65536;
    const int curo = cur * 65536, nxto = (cur ^ 1) * 65536;
    const int k1 = (tt + 1) * 64, k2 = (tt + 2) * 64;

    // ---- phase 0: read A(qi=0) + B(qj=0); stage tile+1 A1,A3 ----
#pragma unroll
    for (int f = 0; f < 4; ++f)
#pragma unroll
      for (int ks = 0; ks < 2; ++ks) af[f][ks] = rdA(buf, 0, f, ks);
#pragma unroll
    for (int g = 0; g < 2; ++g)
#pragma unroll
      for (int ks = 0; ks < 2; ++ks) b0[g][ks] = rdB(buf, 0, g, ks);
    if (tt + 1 < NK) {
      stageA(1, kA(k1), nxto + 8192);
      stageA(3, kA(k1), nxto + 24576);
    }
    asm volatile("s_waitcnt lgkmcnt(8)" ::: "memory");   // pre-drain 12-read phase
    __builtin_amdgcn_sched_barrier(0);
    PH_SYNC();
    DOMFMA(0, 0, af, b0);
    PH_END();

    // ---- phase 1: read B(qj=1); stage tile+2 A0,A2 ----
#pragma unroll
    for (int g = 0; g < 2; ++g)
#pragma unroll
      for (int ks = 0; ks < 2; ++ks) b1[g][ks] = rdB(buf, 1, g, ks);
    if (tt + 2 < NK) {
      stageA(0, kA(k2), curo + 0);
      stageA(2, kA(k2), curo + 16384);
    }
    PH_SYNC();
    DOMFMA(0, 1, af, b1);
    PH_END();

    // ---- phase 2: read A(qi=1); stage tile+2 B0,B1 ----
#pragma unroll
    for (int f = 0; f < 4; ++f)
#pragma unroll
      for (int ks = 0; ks < 2; ++ks) af[f][ks] = rdA(buf, 1, f, ks);
    if (tt + 2 < NK) {
      stageB(0, kB(k2), curo + 32768);
      stageB(1, kB(k2), curo + 40960);
    }
    PH_SYNC();
    DOMFMA(1, 0, af, b0);
    PH_END();

    // ---- phase 3: no reads; stage tile+2 B2,B3; counted vmcnt ----
    if (tt + 2 < NK) {
      stageB(2, kB(k2), curo + 49152);
      stageB(3, kB(k2), curo + 57344);
      asm volatile("s_waitcnt vmcnt(6)" ::: "memory");
    } else {
      asm volatile("s_waitcnt vmcnt(0)" ::: "memory");
    }
    __builtin_amdgcn_sched_barrier(0);
    PH_SYNC();
    DOMFMA(1, 1, af, b1);
    PH_END();
  }

  // ---- epilogue ----
  const int rbase = Ar0 + wm * 128 + kg * 4;
  const int cbase = Br0 + wn * 64 + lr;
#pragma unroll
  for (int rf = 0; rf < 8; ++rf) {
#pragma unroll
    for (int cf = 0; cf < 4; ++cf) {
      const int col = cbase + cf * 16;
#pragma unroll
      for (int q = 0; q < 4; ++q) {
        const int row = rbase + rf * 16 + q;
        float val = acc[rf][cf][q];
        if constexpr (EP == 0) {
          Cf[(size_t)row * NN + col] = val;
        } else {
          if (col < 2048) {
            val += bias[col];
            const unsigned short h = f2bf(val);
            Ob1[(size_t)row * 4096 + col] = h;
            Ob1[(size_t)row * 4096 + 2048 + col] = f2bf(val - bf2f(h));
          } else {
            const int c2 = col - 2048;
            val += bias2[c2];
            const unsigned short h = f2bf(val);
            Ob2[(size_t)row * 4096 + c2] = h;
            Ob2[(size_t)row * 4096 + 2048 + c2] = f2bf(val - bf2f(h));
          }
        }
      }
    }
  }
}

// ---------------------------------------------------------------------------
// GEMM: C[M][N] = A[M][K] @ Bt[N][K]^T  (bf16 MFMA, f32 acc), m97 structure.
// EP: 0=f32(+bias) 1=bf16(+bias) 2=gelu->bf16 4=perm [m][b][z] 5=bf16(+row bias)
// ---------------------------------------------------------------------------
template<int EP>
__global__ __launch_bounds__(256) void gemm_bt(
    const unsigned short* __restrict__ Ah,
    const unsigned short* __restrict__ Bh,
    const float* __restrict__ bias,
    float* __restrict__ Cf, unsigned short* __restrict__ Cb,
    int M, int N, int K, int lda, int ldb) {
  __shared__ unsigned short lds[2][128 * 32];
  const int t = threadIdx.x;
  const int lane = t & 63;
  const int w = t >> 6;
  const int wr = (w >> 1) * 64, wc = (w & 1) * 64;
  const int lr = lane & 15, kg = lane >> 4;
  const size_t Ar0 = (size_t)blockIdx.y * 128;
  const size_t Br0 = (size_t)blockIdx.x * 128;

  f32x4 acc[4][4] = {};

  for (int k0 = 0; k0 < K; k0 += 32) {
#pragma unroll
    for (int rnd = 0; rnd < 2; ++rnd) {
      const int e = t * 8 + rnd * 2048;
      const int row = e >> 5, col = e & 31;
      const size_t ga = (Ar0 + row) * (size_t)lda + (k0 + col);
      const size_t gb = (Br0 + row) * (size_t)ldb + (k0 + col);
      const int lo = (w << 9) + rnd * 2048;   // wave-uniform LDS elem offset
      gload_lds16(Ah + ga, &lds[0][lo]);
      gload_lds16(Bh + gb, &lds[1][lo]);
    }
    __syncthreads();
    bf16x8 ah[4], bh[4];
#pragma unroll
    for (int i = 0; i < 4; ++i) {
      ah[i] = *(const bf16x8*)&lds[0][((wr + i * 16 + lr) << 5) + (kg << 3)];
      bh[i] = *(const bf16x8*)&lds[1][((wc + i * 16 + lr) << 5) + (kg << 3)];
    }
#pragma unroll
    for (int i = 0; i < 4; ++i)
#pragma unroll
      for (int j = 0; j < 4; ++j)
        acc[i][j] = __builtin_amdgcn_mfma_f32_16x16x32_bf16(ah[i], bh[j], acc[i][j], 0, 0, 0);
    __syncthreads();
  }

  const int rb = (int)Ar0 + wr + (lane >> 4) * 4;
  const int cb = (int)Br0 + wc + lr;
#pragma unroll
  for (int i = 0; i < 4; ++i) {
#pragma unroll
    for (int j = 0; j < 4; ++j) {
      const int col = cb + j * 16;
      const float bsv = (EP == 5) ? 0.0f : (bias ? bias[col] : 0.0f);
#pragma unroll
      for (int q = 0; q < 4; ++q) {
        const int row = rb + i * 16 + q;
        const float val = acc[i][j][q] + bsv;
        const size_t o = (size_t)row * N + col;
        if constexpr (EP == 0) {
          Cf[o] = val;
        } else if constexpr (EP == 1) {
          Cb[o] = f2bf(val);
        } else if constexpr (EP == 2) {
          const float ge = 0.5f * val * (1.0f + erff(val * 0.70710678118654752f));
          Cb[o] = f2bf(ge);
        } else if constexpr (EP == 4) {
          const size_t oo = (size_t)(col >> 8) * ((size_t)BB * ZD)
                          + (size_t)row * ZD + (col & 255);
          Cf[oo] = val;
        } else {  // EP == 5: bf16 with ROW bias
          Cb[o] = f2bf(val + bias[row]);
        }
      }
    }
  }
}

// ---------------------------------------------------------------------------
// row softmax over 4096 cols, f32 in -> bf16 out
// ---------------------------------------------------------------------------
__global__ __launch_bounds__(256) void softmax_rows(const float* __restrict__ S,
                                                    unsigned short* __restrict__ P) {
  const int row = blockIdx.x;
  const int t = threadIdx.x;
  const int lane = t & 63, w = t >> 6;
  const float* s = S + (size_t)row * 4096;
  float4 v[4];
  float mx = -3.4e38f;
#pragma unroll
  for (int i = 0; i < 4; ++i) {
    v[i] = *(const float4*)(s + (size_t)(t + 256 * i) * 4);
    mx = fmaxf(mx, fmaxf(fmaxf(v[i].x, v[i].y), fmaxf(v[i].z, v[i].w)));
  }
#pragma unroll
  for (int off = 32; off >= 1; off >>= 1) mx = fmaxf(mx, __shfl_xor(mx, off));
  __shared__ float redm[4], redsum[4];
  if (lane == 0) redm[w] = mx;
  __syncthreads();
  mx = fmaxf(fmaxf(redm[0], redm[1]), fmaxf(redm[2], redm[3]));
  float sum = 0.f;
#pragma unroll
  for (int i = 0; i < 4; ++i) {
    v[i].x = expf(v[i].x - mx);
    v[i].y = expf(v[i].y - mx);
    v[i].z = expf(v[i].z - mx);
    v[i].w = expf(v[i].w - mx);
    sum += v[i].x + v[i].y + v[i].z + v[i].w;
  }
#pragma unroll
  for (int off = 32; off >= 1; off >>= 1) sum += __shfl_xor(sum, off);
  if (lane == 0) redsum[w] = sum;
  __syncthreads();
  sum = redsum[0] + redsum[1] + redsum[2] + redsum[3];
  const float inv = 1.0f / sum;
  unsigned short* p = P + (size_t)row * 4096;
#pragma unroll
  for (int i = 0; i < 4; ++i) {
    ushort4 u;
    u.x = f2bf(v[i].x * inv);
    u.y = f2bf(v[i].y * inv);
    u.z = f2bf(v[i].z * inv);
    u.w = f2bf(v[i].w * inv);
    *(ushort4*)(p + (size_t)(t + 256 * i) * 4) = u;
  }
}

// ---------------------------------------------------------------------------
// layernorm(a + b [+ c]) over 2048 cols; writes bf16 (and optionally f32)
// ZG: 'a' is z_stack [8][4096][256] gathered as x[row][m*256+zd]
// ---------------------------------------------------------------------------
template<bool ZG, bool WF32>
__global__ __launch_bounds__(256) void ln_fused(
    const float* __restrict__ a, const float* __restrict__ b,
    const float* __restrict__ c,
    const float* __restrict__ g, const float* __restrict__ be,
    float* __restrict__ of, unsigned short* __restrict__ ob) {
  const int row = blockIdx.x;
  const int t = threadIdx.x;
  const int lane = t & 63, w = t >> 6;
  const float* br = b + (size_t)row * 2048;
  float4 x[2];
  float s = 0.f, ss = 0.f;
#pragma unroll
  for (int i = 0; i < 2; ++i) {
    const int o = (t + 256 * i) * 4;
    float4 av;
    if constexpr (ZG) {
      av = *(const float4*)(a + ((size_t)(o >> 8) * 4096 + row) * 256 + (o & 255));
    } else {
      av = *(const float4*)(a + (size_t)row * 2048 + o);
    }
    const float4 bv = *(const float4*)(br + o);
    x[i].x = av.x + bv.x; x[i].y = av.y + bv.y;
    x[i].z = av.z + bv.z; x[i].w = av.w + bv.w;
    if (c) {
      const float4 cv = *(const float4*)(c + (size_t)row * 2048 + o);
      x[i].x += cv.x; x[i].y += cv.y; x[i].z += cv.z; x[i].w += cv.w;
    }
    s  += x[i].x + x[i].y + x[i].z + x[i].w;
    ss += x[i].x * x[i].x + x[i].y * x[i].y + x[i].z * x[i].z + x[i].w * x[i].w;
  }
#pragma unroll
  for (int off = 32; off >= 1; off >>= 1) {
    s  += __shfl_xor(s, off);
    ss += __shfl_xor(ss, off);
  }
  __shared__ float rs[4], rss[4];
  if (lane == 0) { rs[w] = s; rss[w] = ss; }
  __syncthreads();
  s  = rs[0] + rs[1] + rs[2] + rs[3];
  ss = rss[0] + rss[1] + rss[2] + rss[3];
  const float mu  = s * (1.0f / 2048.0f);
  const float var = ss * (1.0f / 2048.0f) - mu * mu;
  const float inv = rsqrtf(var + 1e-5f);
#pragma unroll
  for (int i = 0; i < 2; ++i) {
    const int o = (t + 256 * i) * 4;
    const float4 gv  = *(const float4*)(g + o);
    const float4 bev = *(const float4*)(be + o);
    float4 y;
    y.x = (x[i].x - mu) * inv * gv.x + bev.x;
    y.y = (x[i].y - mu) * inv * gv.y + bev.y;
    y.z = (x[i].z - mu) * inv * gv.z + bev.z;
    y.w = (x[i].w - mu) * inv * gv.w + bev.w;
    if constexpr (WF32) *(float4*)(of + (size_t)row * 2048 + o) = y;
    ushort4 u;
    u.x = f2bf(y.x); u.y = f2bf(y.y); u.z = f2bf(y.z); u.w = f2bf(y.w);
    *(ushort4*)(ob + (size_t)row * 2048 + o) = u;
  }
}

// ---------------------------------------------------------------------------
extern "C" void kernel_launch(void* const* d_in, const int* in_sizes, int n_in,
                              void* d_out, int out_size, void* d_ws, size_t ws_size,
                              hipStream_t stream) {
  (void)in_sizes; (void)n_in; (void)out_size;
  const float* z    = (const float*)d_in[0];
  const float* Wq   = (const float*)d_in[1];
  const float* bq   = (const float*)d_in[2];
  const float* Wk   = (const float*)d_in[3];
  const float* bk   = (const float*)d_in[4];
  const float* Wv   = (const float*)d_in[5];
  const float* bv   = (const float*)d_in[6];
  const float* W1   = (const float*)d_in[7];
  const float* b1   = (const float*)d_in[8];
  const float* W2   = (const float*)d_in[9];
  const float* b2   = (const float*)d_in[10];
  const float* ln1g = (const float*)d_in[11];
  const float* ln1b = (const float*)d_in[12];
  const float* ln2g = (const float*)d_in[13];
  const float* ln2b = (const float*)d_in[14];
  const float* Wys  = (const float*)d_in[15];
  const float* bys  = (const float*)d_in[16];
  const float* Ws   = (const float*)d_in[17];
  const float* bs   = (const float*)d_in[18];
  float* out = (float*)d_out;
  char* ws = (char*)d_ws;

  // ---- workspace arena (lifetime-aliased), 216 MB total ----
  const size_t MB = 1048576;
  const size_t off_h2   = 0;          // f32 [4096][2048], MLP2 out
  const size_t off_x2   = 32 * MB;    // bf16 [4096][4096] [xh|xl], until QKproj
  const size_t off_S    = 32 * MB;    // f32 [4096][4096], after QKproj, until softmax
  const size_t off_att  = 32 * MB;    // f32 2x[4096][2048] split-K partials, after softmax
  const size_t off_Bqk  = 64 * MB;    // bf16 [4096][4096], until QKproj
  const size_t off_Aq   = 96 * MB;    // bf16 [4096][4096] [qh|ql], until S
  const size_t off_P    = 96 * MB;    // bf16 [4096][4096], after S, until PV
  const size_t off_x1f  = 96 * MB;    // f32 [4096][2048], after PV
  const size_t off_Btk  = 128 * MB;   // bf16 [4096][4096] [kh|kl], until S
  const size_t off_hmid = 128 * MB;   // bf16 [4096][1024], after S
  const size_t off_ybbf = 136 * MB;   // bf16 [4096][1024]
  const size_t off_x1bf = 160 * MB;   // bf16 [4096][2048], LN1 out
  const size_t off_Vt   = 176 * MB;   // bf16 [2048][4096], until PV
  const size_t off_x2bf = 176 * MB;   // bf16 [4096][2048], after PV
  const size_t off_Wvt  = 192 * MB;   // bf16 [2048][2048]
  const size_t off_W1t  = 200 * MB;   // bf16 [1024][2048]
  const size_t off_W2t  = 204 * MB;   // bf16 [2048][1024]
  const size_t off_Wyst = 208 * MB;   // bf16 [1024][2048]
  const size_t off_Wst  = 212 * MB;   // bf16 8x[256][1024]
  if (ws_size < 216 * MB) return;

#define F32P(o) ((float*)(ws + (o)))
#define BFP(o)  ((unsigned short*)(ws + (o)))

  const int LDSB = 131072;

  // prep (2 launches)
  pack_x<<<8192, 256, 0, stream>>>(z, BFP(off_x2));
  transpose_all<<<20480, dim3(32, 8), 0, stream>>>(Wq, Wk, Wv, W1, W2, Wys, Ws,
      BFP(off_Bqk), BFP(off_Wvt), BFP(off_W1t), BFP(off_W2t), BFP(off_Wyst), BFP(off_Wst));

  // Vt = Wv^T @ x^T directly (M=2048 n-rows, N=4096 batch, row bias bv)
  gemm_bt<5><<<dim3(32, 16), 256, 0, stream>>>(BFP(off_Wvt), BFP(off_x2), bv,
      nullptr, BFP(off_Vt), 2048, 4096, 2048, 2048, 4096);

  // fused Q+K projection with hi/lo split epilogue (K=6144 virtual)  [8-phase]
  gemm256<1, true, 0, 6144, 4096, 4096, 4096, 16><<<256, 512, LDSB, stream>>>(
      BFP(off_x2), BFP(off_Bqk), bq, bk, nullptr, BFP(off_Aq), BFP(off_Btk));

  // S = q @ k^T with split (K=6144 virtual), f32 out  [8-phase]
  gemm256<0, true, 0, 6144, 4096, 4096, 4096, 16><<<256, 512, LDSB, stream>>>(
      BFP(off_Aq), BFP(off_Btk), nullptr, nullptr, F32P(off_S), nullptr, nullptr);

  // softmax -> P (bf16); att = P @ V via split-K=2 gemm256 (partials att0,att1)
  softmax_rows<<<4096, 256, 0, stream>>>(F32P(off_S), BFP(off_P));
  gemm256<0, false, 1, 2048, 4096, 4096, 2048, 8><<<256, 512, LDSB, stream>>>(
      BFP(off_P), BFP(off_Vt), nullptr, nullptr, F32P(off_att), nullptr, nullptr);
  ln_fused<true, true ><<<4096, 256, 0, stream>>>(z, F32P(off_att),
      F32P(off_att + 32 * MB), ln1g, ln1b, F32P(off_x1f), BFP(off_x1bf));

  // MLP  [m97 structure]
  gemm_bt<2><<<dim3(8, 32), 256, 0, stream>>>(BFP(off_x1bf), BFP(off_W1t), b1,
      nullptr, BFP(off_hmid), 4096, 1024, 2048, 2048, 2048);
  gemm_bt<0><<<dim3(16, 32), 256, 0, stream>>>(BFP(off_hmid), BFP(off_W2t), b2,
      F32P(off_h2), nullptr, 4096, 2048, 1024, 1024, 1024);
  ln_fused<false, false><<<4096, 256, 0, stream>>>(F32P(off_x1f), F32P(off_h2),
      nullptr, ln2g, ln2b, nullptr, BFP(off_x2bf));

  // output head  [m97 structure]
  gemm_bt<1><<<dim3(8, 32), 256, 0, stream>>>(BFP(off_x2bf), BFP(off_Wyst), bys,
      nullptr, BFP(off_ybbf), 4096, 1024, 2048, 2048, 2048);
  gemm_bt<4><<<dim3(16, 32), 256, 0, stream>>>(BFP(off_ybbf), BFP(off_Wst), bs,
      out, nullptr, 4096, 2048, 1024, 1024, 1024);
}